// Round 1
// baseline (89.057 us; speedup 1.0000x reference)
//
#include <hip/hip_runtime.h>
#include <hip/hip_bf16.h>

#define M_PTS 16384
#define N_SPT 16384
#define DIM   64
#define NSL   16                 // n-slices
#define SLN   (N_SPT / NSL)      // 1024 n-rows per block
#define TSTEPS (SLN / 16)        // 64 MFMA steps per block

typedef __attribute__((ext_vector_type(8))) short bf16x8;
typedef __attribute__((ext_vector_type(4))) float f32x4;

#define LOG2E 1.4426950408889634f

__device__ __forceinline__ unsigned short f32_bf16_rne(float f) {
  unsigned int x = __float_as_uint(f);
  x = x + 0x7fffu + ((x >> 16) & 1u);
  return (unsigned short)(x >> 16);
}
__device__ __forceinline__ float bf16_f32(unsigned short u) {
  return __uint_as_float(((unsigned int)u) << 16);
}

// Prep (unchanged, known-good):
//  points : store p~ = bf16(scale * p); Em = exp2(-|p~|^2/(2*scale))
//  spatial: store s~ = bf16(s); En = w * exp2(-|s~|^2 * scale/2)
// Em*En*exp2(p~ . s~) == exact Gaussian of the rounded points.
__global__ __launch_bounds__(256) void kde_prep(
    const float* __restrict__ pts, const float* __restrict__ spt,
    const float* __restrict__ w, const float* __restrict__ bw,
    unsigned short* __restrict__ ptsb, unsigned short* __restrict__ spb,
    float* __restrict__ Em, float* __restrict__ En) {
  const float b = bw[0];
  const float scale = LOG2E / (b * b);
  const float c1 = 0.5f * scale;
  const float invc = (b * b) / (2.0f * LOG2E);
  const int tid = threadIdx.x;
  const bool isP = blockIdx.x < (M_PTS / 16);
  const int r0 = isP ? (blockIdx.x * 16) : ((blockIdx.x - M_PTS / 16) * 16);
  const float* __restrict__ src = isP ? pts : spt;
  unsigned short* __restrict__ dst = isP ? ptsb : spb;

  size_t off = (size_t)r0 * DIM + (size_t)tid * 4;
  float4 v = *reinterpret_cast<const float4*>(src + off);
  if (isP) { v.x *= scale; v.y *= scale; v.z *= scale; v.w *= scale; }
  ushort4 u;
  u.x = f32_bf16_rne(v.x); u.y = f32_bf16_rne(v.y);
  u.z = f32_bf16_rne(v.z); u.w = f32_bf16_rne(v.w);
  float ax = bf16_f32(u.x), ay = bf16_f32(u.y);
  float az = bf16_f32(u.z), aw = bf16_f32(u.w);
  float sq = ax * ax + ay * ay + az * az + aw * aw;
  *reinterpret_cast<ushort4*>(dst + off) = u;

  sq += __shfl_xor(sq, 1);
  sq += __shfl_xor(sq, 2);
  sq += __shfl_xor(sq, 4);
  sq += __shfl_xor(sq, 8);
  if ((tid & 15) == 0) {
    int row = r0 + (tid >> 4);
    if (isP) Em[row] = exp2f(-sq * invc);
    else     En[row] = w[row] * exp2f(-sq * c1);
  }
}

// Main, v2: barrier-free. The 128 KB B-slice is L2-resident (shared by 64
// blocks), so LDS staging was pure overhead: its alias-poisoned ds_reads
// exposed ~120+ cyc of lgkm wait per step plus 8 vmcnt(0)+barrier drains.
// Now B fragments are loaded straight from global into registers with a
// ~2-step software prefetch (counted vmcnt, loads stay in flight); the only
// barrier is the one-time En-slice fill. MFMA C-init uses a hoisted zero
// quad (no per-step accvgpr/mov zeroing). Block mapping is XCD-chunked:
// each XCD covers 2 slices x 64 m-blocks (~2.25 MB L2 footprint).
__global__ __launch_bounds__(256) void kde_main(
    const unsigned short* __restrict__ ptsb,
    const unsigned short* __restrict__ spb,
    const float* __restrict__ En,
    float* __restrict__ partials) {
  __shared__ float lden[SLN];  // 4 KB, read-only after one barrier

  const int tid = threadIdx.x;
  const int lane = tid & 63;
  const int wave = tid >> 6;
  const int lr = lane & 15;   // tile row (A) / tile col (B)
  const int lg = lane >> 4;   // k-group

  // XCD-chunked mapping: lid%8 = XCD (dispatch round-robin); each XCD gets
  // slices {2k, 2k+1} over all 64 m-blocks. Bijective over (s, mb).
  const int lid = blockIdx.x;
  const int q = lid >> 3;
  const int s = (lid & 7) * 2 + (q >> 6);
  const int mb = q & 63;
  const int mbase = mb * 256 + wave * 64;

#pragma unroll
  for (int k = 0; k < SLN / 256; ++k)
    lden[tid + k * 256] = En[s * SLN + tid + k * 256];

  // A fragments (read once; 32 VGPRs).
  bf16x8 a[4][2];
#pragma unroll
  for (int t = 0; t < 4; ++t)
#pragma unroll
    for (int h = 0; h < 2; ++h)
      a[t][h] = *reinterpret_cast<const bf16x8*>(
          ptsb + (size_t)(mbase + t * 16 + lr) * DIM + h * 32 + lg * 8);

  __syncthreads();  // lden ready; no further barriers

  // Per-lane B pointer: step st fragment b0 at st*2048 + lr*128 + lg*16,
  // b1 at +64 bytes (same layout the LDS path used, minus the swizzle).
  const char* bptr =
      (const char*)(spb + (size_t)s * SLN * DIM) + lr * 128 + lg * 16;
  const float* enr = lden + lr;

  const f32x4 kz = {0.0f, 0.0f, 0.0f, 0.0f};  // shared C-init quad
  float sum[4][4] = {{0.0f, 0.0f, 0.0f, 0.0f}, {0.0f, 0.0f, 0.0f, 0.0f},
                     {0.0f, 0.0f, 0.0f, 0.0f}, {0.0f, 0.0f, 0.0f, 0.0f}};
  f32x4 cA[4], cB[4];

#define MS(C, B0, B1)                                                        \
  {                                                                          \
    _Pragma("unroll") for (int t = 0; t < 4; ++t) {                          \
      C[t] = __builtin_amdgcn_mfma_f32_16x16x32_bf16(a[t][0], B0, kz,        \
                                                     0, 0, 0);               \
      C[t] = __builtin_amdgcn_mfma_f32_16x16x32_bf16(a[t][1], B1, C[t],      \
                                                     0, 0, 0);               \
    }                                                                        \
  }

#define FIN(C, EN)                                                           \
  {                                                                          \
    float en = (EN);                                                         \
    _Pragma("unroll") for (int t = 0; t < 4; ++t) {                          \
      _Pragma("unroll") for (int rr = 0; rr < 4; ++rr) {                     \
        float e;                                                             \
        asm("v_exp_f32 %0, %1" : "=v"(e) : "v"(C[t][rr]));                   \
        sum[t][rr] = fmaf(en, e, sum[t][rr]);                                \
      }                                                                      \
    }                                                                        \
  }

  // Register prefetch, 2 steps deep (even/odd slots). Loads for step st are
  // issued ~1 full step before consumption -> counted vmcnt, no drain.
  bf16x8 e0, e1, o0, o1;
  e0 = *reinterpret_cast<const bf16x8*>(bptr);
  e1 = *reinterpret_cast<const bf16x8*>(bptr + 64);
  o0 = *reinterpret_cast<const bf16x8*>(bptr + 2048);
  o1 = *reinterpret_cast<const bf16x8*>(bptr + 2048 + 64);

  // Peeled iteration 0 (steps 0,1): no FINISH for step -1.
  MS(cA, e0, e1)
  e0 = *reinterpret_cast<const bf16x8*>(bptr + 2 * 2048);
  e1 = *reinterpret_cast<const bf16x8*>(bptr + 2 * 2048 + 64);
  MS(cB, o0, o1)
  FIN(cA, enr[0])
  o0 = *reinterpret_cast<const bf16x8*>(bptr + 3 * 2048);
  o1 = *reinterpret_cast<const bf16x8*>(bptr + 3 * 2048 + 64);

  const char* bp = bptr + 4 * 2048;
  for (int u = 1; u < 32; ++u, bp += 2 * 2048) {
    // step 2u
    MS(cA, e0, e1)
    FIN(cB, enr[(2 * u - 1) * 16])
    e0 = *reinterpret_cast<const bf16x8*>(bp);
    e1 = *reinterpret_cast<const bf16x8*>(bp + 64);
    // step 2u+1
    MS(cB, o0, o1)
    FIN(cA, enr[(2 * u) * 16])
    o0 = *reinterpret_cast<const bf16x8*>(bp + 2048);
    o1 = *reinterpret_cast<const bf16x8*>(bp + 2048 + 64);
    // Tail note: u==31 issues loads for steps 64/65 (never consumed).
    // They overread ~4 KB past the s==15 slice into the Em buffer, which
    // is mapped workspace -> safe.
  }
  FIN(cB, enr[63 * 16])
#undef MS
#undef FIN

  // Reduce the 16 n-columns held across lanes of each k-group.
#pragma unroll
  for (int t = 0; t < 4; ++t)
#pragma unroll
    for (int r = 0; r < 4; ++r) {
      float v = sum[t][r];
      v += __shfl_xor(v, 1);
      v += __shfl_xor(v, 2);
      v += __shfl_xor(v, 4);
      v += __shfl_xor(v, 8);
      sum[t][r] = v;
    }
  if (lr == 0) {
#pragma unroll
    for (int t = 0; t < 4; ++t)
#pragma unroll
      for (int r = 0; r < 4; ++r) {
        int row = mbase + t * 16 + lg * 4 + r;
        partials[(size_t)s * M_PTS + row] = sum[t][r];
      }
  }
}

__global__ __launch_bounds__(256) void kde_reduce(
    const float* __restrict__ partials, const float* __restrict__ Em,
    float* __restrict__ out) {
  int m = blockIdx.x * 256 + threadIdx.x;
  float t = 0.0f;
#pragma unroll
  for (int s2 = 0; s2 < NSL; ++s2)
    t += partials[(size_t)s2 * M_PTS + m];
  out[m] = Em[m] * t;
}

extern "C" void kernel_launch(void* const* d_in, const int* in_sizes, int n_in,
                              void* d_out, int out_size, void* d_ws, size_t ws_size,
                              hipStream_t stream) {
  const float* pts = (const float*)d_in[0];   // [M, 64]
  const float* spt = (const float*)d_in[1];   // [N, 64]
  const float* w   = (const float*)d_in[2];   // [N]
  const float* bw  = (const float*)d_in[3];   // scalar
  float* out = (float*)d_out;                 // [M] fp32

  // ws: ptsb 2MB | spb 2MB | Em 64KB | En 64KB | partials 1MB
  // (Em immediately after spb also absorbs the benign prefetch overread.)
  char* ws = (char*)d_ws;
  unsigned short* ptsb = (unsigned short*)ws;
  unsigned short* spb  = (unsigned short*)(ws + (size_t)M_PTS * DIM * 2);
  float* Em = (float*)(ws + (size_t)(M_PTS + N_SPT) * DIM * 2);
  float* En = Em + M_PTS;
  float* partials = En + N_SPT;

  kde_prep<<<dim3((M_PTS + N_SPT) / 16), 256, 0, stream>>>(
      pts, spt, w, bw, ptsb, spb, Em, En);
  kde_main<<<dim3(M_PTS / 256 * NSL), 256, 0, stream>>>(
      ptsb, spb, En, partials);
  kde_reduce<<<dim3(M_PTS / 256), 256, 0, stream>>>(partials, Em, out);
}

// Round 4
// 75.224 us; speedup vs baseline: 1.1839x; 1.1839x over previous
//
#include <hip/hip_runtime.h>
#include <hip/hip_bf16.h>

#define M_PTS 16384
#define N_SPT 16384
#define DIM   64
#define NSL   16                 // n-slices
#define SLN   (N_SPT / NSL)      // 1024 n-rows per block
#define TSTEPS (SLN / 16)        // 64 MFMA steps per block

typedef __attribute__((ext_vector_type(8))) short bf16x8;
typedef __attribute__((ext_vector_type(4))) float f32x4;

#define LOG2E 1.4426950408889634f

__device__ __forceinline__ unsigned short f32_bf16_rne(float f) {
  unsigned int x = __float_as_uint(f);
  x = x + 0x7fffu + ((x >> 16) & 1u);
  return (unsigned short)(x >> 16);
}
__device__ __forceinline__ float bf16_f32(unsigned short u) {
  return __uint_as_float(((unsigned int)u) << 16);
}

// Prep (unchanged, known-good):
//  points : store p~ = bf16(scale * p); Em = exp2(-|p~|^2/(2*scale))
//  spatial: store s~ = bf16(s); En = w * exp2(-|s~|^2 * scale/2)
// Em*En*exp2(p~ . s~) == exact Gaussian of the rounded points.
__global__ __launch_bounds__(256) void kde_prep(
    const float* __restrict__ pts, const float* __restrict__ spt,
    const float* __restrict__ w, const float* __restrict__ bw,
    unsigned short* __restrict__ ptsb, unsigned short* __restrict__ spb,
    float* __restrict__ Em, float* __restrict__ En) {
  const float b = bw[0];
  const float scale = LOG2E / (b * b);
  const float c1 = 0.5f * scale;
  const float invc = (b * b) / (2.0f * LOG2E);
  const int tid = threadIdx.x;
  const bool isP = blockIdx.x < (M_PTS / 16);
  const int r0 = isP ? (blockIdx.x * 16) : ((blockIdx.x - M_PTS / 16) * 16);
  const float* __restrict__ src = isP ? pts : spt;
  unsigned short* __restrict__ dst = isP ? ptsb : spb;

  size_t off = (size_t)r0 * DIM + (size_t)tid * 4;
  float4 v = *reinterpret_cast<const float4*>(src + off);
  if (isP) { v.x *= scale; v.y *= scale; v.z *= scale; v.w *= scale; }
  ushort4 u;
  u.x = f32_bf16_rne(v.x); u.y = f32_bf16_rne(v.y);
  u.z = f32_bf16_rne(v.z); u.w = f32_bf16_rne(v.w);
  float ax = bf16_f32(u.x), ay = bf16_f32(u.y);
  float az = bf16_f32(u.z), aw = bf16_f32(u.w);
  float sq = ax * ax + ay * ay + az * az + aw * aw;
  *reinterpret_cast<ushort4*>(dst + off) = u;

  sq += __shfl_xor(sq, 1);
  sq += __shfl_xor(sq, 2);
  sq += __shfl_xor(sq, 4);
  sq += __shfl_xor(sq, 8);
  if ((tid & 15) == 0) {
    int row = r0 + (tid >> 4);
    if (isP) Em[row] = exp2f(-sq * invc);
    else     En[row] = w[row] * exp2f(-sq * c1);
  }
}

// Main v5: v4's barrier-free direct-global structure (4-step register
// prefetch, named fragment sets, shared kz C-init, XCD-chunked mapping)
// with the __launch_bounds__ min-waves cap REMOVED. v3/v4 both failed
// nondeterministically with (256,4) forcing VGPR<=128 under ~140-reg
// pressure (spill-to-scratch corruption); the passing v0/v2 had no cap.
// Accumulation order is identical to the passing v2 -> same absmax.
__global__ __launch_bounds__(256) void kde_main(
    const unsigned short* __restrict__ ptsb,
    const unsigned short* __restrict__ spb,
    const float* __restrict__ En,
    float* __restrict__ partials) {
  __shared__ float lden[SLN];  // 4 KB, read-only after one barrier

  const int tid = threadIdx.x;
  const int lane = tid & 63;
  const int wave = tid >> 6;
  const int lr = lane & 15;   // tile row (A) / tile col (B)
  const int lg = lane >> 4;   // k-group

  // XCD-chunked mapping: lid%8 = XCD (dispatch round-robin); each XCD gets
  // slices {2k, 2k+1} over all 64 m-blocks. Bijective over (s, mb).
  const int lid = blockIdx.x;
  const int q = lid >> 3;
  const int s = (lid & 7) * 2 + (q >> 6);
  const int mb = q & 63;
  const int mbase = mb * 256 + wave * 64;

#pragma unroll
  for (int k = 0; k < SLN / 256; ++k)
    lden[tid + k * 256] = En[s * SLN + tid + k * 256];

  // A fragments (read once; 32 VGPRs).
  bf16x8 a[4][2];
#pragma unroll
  for (int t = 0; t < 4; ++t)
#pragma unroll
    for (int h = 0; h < 2; ++h)
      a[t][h] = *reinterpret_cast<const bf16x8*>(
          ptsb + (size_t)(mbase + t * 16 + lr) * DIM + h * 32 + lg * 8);

  __syncthreads();  // lden ready; no further barriers

  // Per-lane B pointer: step st fragment b0 at st*2048 + lr*128 + lg*16,
  // b1 at +64 bytes.
  const char* bptr =
      (const char*)(spb + (size_t)s * SLN * DIM) + lr * 128 + lg * 16;
  const float* enr = lden + lr;

  const f32x4 kz = {0.0f, 0.0f, 0.0f, 0.0f};  // shared C-init quad
  float sum[4][4] = {{0.0f, 0.0f, 0.0f, 0.0f}, {0.0f, 0.0f, 0.0f, 0.0f},
                     {0.0f, 0.0f, 0.0f, 0.0f}, {0.0f, 0.0f, 0.0f, 0.0f}};
  f32x4 cA[4], cB[4];

#define MS(C, B0, B1)                                                        \
  {                                                                          \
    _Pragma("unroll") for (int t = 0; t < 4; ++t) {                          \
      C[t] = __builtin_amdgcn_mfma_f32_16x16x32_bf16(a[t][0], B0, kz,        \
                                                     0, 0, 0);               \
      C[t] = __builtin_amdgcn_mfma_f32_16x16x32_bf16(a[t][1], B1, C[t],      \
                                                     0, 0, 0);               \
    }                                                                        \
  }

#define FIN(C, EN)                                                           \
  {                                                                          \
    float en = (EN);                                                         \
    _Pragma("unroll") for (int t = 0; t < 4; ++t) {                          \
      _Pragma("unroll") for (int rr = 0; rr < 4; ++rr) {                     \
        float e;                                                             \
        asm("v_exp_f32 %0, %1" : "=v"(e) : "v"(C[t][rr]));                   \
        sum[t][rr] = fmaf(en, e, sum[t][rr]);                                \
      }                                                                      \
    }                                                                        \
  }

#define LD(S0, S1, OFF)                                                      \
  S0 = *reinterpret_cast<const bf16x8*>(bptr + (OFF));                       \
  S1 = *reinterpret_cast<const bf16x8*>(bptr + (OFF) + 64);

  // Four named prefetch sets (depth ~4 steps in flight).
  bf16x8 q00, q01, q10, q11, q20, q21, q30, q31;
  LD(q00, q01, 0 * 2048)
  LD(q10, q11, 1 * 2048)
  LD(q20, q21, 2 * 2048)
  LD(q30, q31, 3 * 2048)

  // Peeled steps 0,1 (no FIN for step -1).
  MS(cA, q00, q01)
  LD(q00, q01, 4 * 2048)
  MS(cB, q10, q11)
  FIN(cA, enr[0])
  LD(q10, q11, 5 * 2048)

  // Steady state: 15 iterations x 4 steps, computing st 4u+2 .. 4u+5 and
  // loading st 4u+6 .. 4u+9. Final iteration's loads (st 64,65) overread
  // ~4 KB past the s==15 slice into the Em workspace buffer -> benign
  // (same overread existed in the passing v2).
  const char* bp = bptr + 6 * 2048;   // load cursor (st 4u+6)
  const float* enp = enr + 1 * 16;    // FIN cursor (st 4u+1)
  for (int u = 0; u < 15; ++u, bp += 4 * 2048, enp += 64) {
    MS(cA, q20, q21)
    FIN(cB, enp[0])
    q20 = *reinterpret_cast<const bf16x8*>(bp);
    q21 = *reinterpret_cast<const bf16x8*>(bp + 64);
    MS(cB, q30, q31)
    FIN(cA, enp[16])
    q30 = *reinterpret_cast<const bf16x8*>(bp + 2048);
    q31 = *reinterpret_cast<const bf16x8*>(bp + 2048 + 64);
    MS(cA, q00, q01)
    FIN(cB, enp[32])
    q00 = *reinterpret_cast<const bf16x8*>(bp + 2 * 2048);
    q01 = *reinterpret_cast<const bf16x8*>(bp + 2 * 2048 + 64);
    MS(cB, q10, q11)
    FIN(cA, enp[48])
    q10 = *reinterpret_cast<const bf16x8*>(bp + 3 * 2048);
    q11 = *reinterpret_cast<const bf16x8*>(bp + 3 * 2048 + 64);
  }

  // Epilogue: steps 62, 63.
  MS(cA, q20, q21)
  FIN(cB, enr[61 * 16])
  MS(cB, q30, q31)
  FIN(cA, enr[62 * 16])
  FIN(cB, enr[63 * 16])
#undef MS
#undef FIN
#undef LD

  // Reduce the 16 n-columns held across lanes of each k-group.
#pragma unroll
  for (int t = 0; t < 4; ++t)
#pragma unroll
    for (int r = 0; r < 4; ++r) {
      float v = sum[t][r];
      v += __shfl_xor(v, 1);
      v += __shfl_xor(v, 2);
      v += __shfl_xor(v, 4);
      v += __shfl_xor(v, 8);
      sum[t][r] = v;
    }
  if (lr == 0) {
#pragma unroll
    for (int t = 0; t < 4; ++t)
#pragma unroll
      for (int r = 0; r < 4; ++r) {
        int row = mbase + t * 16 + lg * 4 + r;
        partials[(size_t)s * M_PTS + row] = sum[t][r];
      }
  }
}

__global__ __launch_bounds__(256) void kde_reduce(
    const float* __restrict__ partials, const float* __restrict__ Em,
    float* __restrict__ out) {
  int m = blockIdx.x * 256 + threadIdx.x;
  float t = 0.0f;
#pragma unroll
  for (int s2 = 0; s2 < NSL; ++s2)
    t += partials[(size_t)s2 * M_PTS + m];
  out[m] = Em[m] * t;
}

extern "C" void kernel_launch(void* const* d_in, const int* in_sizes, int n_in,
                              void* d_out, int out_size, void* d_ws, size_t ws_size,
                              hipStream_t stream) {
  const float* pts = (const float*)d_in[0];   // [M, 64]
  const float* spt = (const float*)d_in[1];   // [N, 64]
  const float* w   = (const float*)d_in[2];   // [N]
  const float* bw  = (const float*)d_in[3];   // scalar
  float* out = (float*)d_out;                 // [M] fp32

  // ws: ptsb 2MB | spb 2MB | Em 64KB | En 64KB | partials 1MB
  // (Em immediately after spb absorbs the benign tail prefetch overread.)
  char* ws = (char*)d_ws;
  unsigned short* ptsb = (unsigned short*)ws;
  unsigned short* spb  = (unsigned short*)(ws + (size_t)M_PTS * DIM * 2);
  float* Em = (float*)(ws + (size_t)(M_PTS + N_SPT) * DIM * 2);
  float* En = Em + M_PTS;
  float* partials = En + N_SPT;

  kde_prep<<<dim3((M_PTS + N_SPT) / 16), 256, 0, stream>>>(
      pts, spt, w, bw, ptsb, spb, Em, En);
  kde_main<<<dim3(M_PTS / 256 * NSL), 256, 0, stream>>>(
      ptsb, spb, En, partials);
  kde_reduce<<<dim3(M_PTS / 256), 256, 0, stream>>>(partials, Em, out);
}

// Round 5
// 71.286 us; speedup vs baseline: 1.2493x; 1.0552x over previous
//
#include <hip/hip_runtime.h>
#include <hip/hip_bf16.h>

#define M_PTS 16384
#define N_SPT 16384
#define DIM   64
#define NSL   16                      // n-slices (blockIdx.y)
#define SLN   (N_SPT / NSL)           // 1024 n-rows per block
#define BUFROWS 128                   // n-rows per stage round
#define BUFBYTES (BUFROWS * DIM * 2)  // 16 KB per buffer
#define ROUNDS (SLN / BUFROWS)        // 8
#define STEPS  (BUFROWS / 16)         // 8 MFMA steps per round

typedef __attribute__((ext_vector_type(8))) short bf16x8;
typedef __attribute__((ext_vector_type(4))) float f32x4;

#define LOG2E 1.4426950408889634f

__device__ __forceinline__ unsigned short f32_bf16_rne(float f) {
  unsigned int x = __float_as_uint(f);
  x = x + 0x7fffu + ((x >> 16) & 1u);
  return (unsigned short)(x >> 16);
}
__device__ __forceinline__ float bf16_f32(unsigned short u) {
  return __uint_as_float(((unsigned int)u) << 16);
}

// Prep (unchanged, known-good):
//  points : store p~ = bf16(scale * p); Em = exp2(-|p~|^2/(2*scale))
//  spatial: store s~ = bf16(s); En = w * exp2(-|s~|^2 * scale/2)
// Em*En*exp2(p~ . s~) == exact Gaussian of the rounded points.
__global__ __launch_bounds__(256) void kde_prep(
    const float* __restrict__ pts, const float* __restrict__ spt,
    const float* __restrict__ w, const float* __restrict__ bw,
    unsigned short* __restrict__ ptsb, unsigned short* __restrict__ spb,
    float* __restrict__ Em, float* __restrict__ En) {
  const float b = bw[0];
  const float scale = LOG2E / (b * b);
  const float c1 = 0.5f * scale;
  const float invc = (b * b) / (2.0f * LOG2E);
  const int tid = threadIdx.x;
  const bool isP = blockIdx.x < (M_PTS / 16);
  const int r0 = isP ? (blockIdx.x * 16) : ((blockIdx.x - M_PTS / 16) * 16);
  const float* __restrict__ src = isP ? pts : spt;
  unsigned short* __restrict__ dst = isP ? ptsb : spb;

  size_t off = (size_t)r0 * DIM + (size_t)tid * 4;
  float4 v = *reinterpret_cast<const float4*>(src + off);
  if (isP) { v.x *= scale; v.y *= scale; v.z *= scale; v.w *= scale; }
  ushort4 u;
  u.x = f32_bf16_rne(v.x); u.y = f32_bf16_rne(v.y);
  u.z = f32_bf16_rne(v.z); u.w = f32_bf16_rne(v.w);
  float ax = bf16_f32(u.x), ay = bf16_f32(u.y);
  float az = bf16_f32(u.z), aw = bf16_f32(u.w);
  float sq = ax * ax + ay * ay + az * az + aw * aw;
  *reinterpret_cast<ushort4*>(dst + off) = u;

  sq += __shfl_xor(sq, 1);
  sq += __shfl_xor(sq, 2);
  sq += __shfl_xor(sq, 4);
  sq += __shfl_xor(sq, 8);
  if ((tid & 15) == 0) {
    int row = r0 + (tid >> 4);
    if (isP) Em[row] = exp2f(-sq * invc);
    else     En[row] = w[row] * exp2f(-sq * c1);
  }
}

// Main v6 = v3 structure WITHOUT the __launch_bounds__ min-waves cap.
// (v4 FAIL-with-cap vs v5 PASS-without-cap A/B-proved the (256,4) cap
// caused spill corruption; v3 carried the same cap and was never actually
// perf-tested. Its barrier structure is hazard-free: all ds_reads drain at
// each __syncthreads, the DMA targets the opposite buffer and is drained by
// vmcnt(0) before the barrier that releases readers.)
//  - STAGE(r+1) issued AFTER the last ds_read of round r: the compiler's
//    conservative DMA-vs-ds_read alias wait can no longer serialize round-r
//    compute on round-(r+1) DMA. DMA still gets ~2 MFMA steps + barrier in
//    flight before the round-end vmcnt(0) drain.
//  - Explicit 1-step register double-buffer (E/O) for B fragments: each
//    ds_read_b128 pair has a full MFMA+exp step as lgkm shadow.
//  - MFMA C-init via shared zero quad kz (no per-step acc zeroing / WAR).
//  - En scalars consumed after the STAGE are preloaded before it.
__global__ __launch_bounds__(256) void kde_main(
    const unsigned short* __restrict__ ptsb,
    const unsigned short* __restrict__ spb,
    const float* __restrict__ En,
    float* __restrict__ partials) {
  __shared__ __align__(16) char ldsb[2 * BUFBYTES];  // 32 KB double buffer
  __shared__ float lden[SLN];                        // 4 KB En slice

  const int tid = threadIdx.x;
  const int lane = tid & 63;
  const int wave = tid >> 6;
  const int lr = lane & 15;   // tile row (A) / tile col (B)
  const int lg = lane >> 4;   // k-group
  const int mbase = blockIdx.x * 256 + wave * 64;
  const int s = blockIdx.y;

#pragma unroll
  for (int k = 0; k < SLN / 256; ++k)
    lden[tid + k * 256] = En[s * SLN + tid + k * 256];

  // A fragments (read once; 32 VGPRs).
  bf16x8 a[4][2];
#pragma unroll
  for (int t = 0; t < 4; ++t)
#pragma unroll
    for (int h = 0; h < 2; ++h)
      a[t][h] = *reinterpret_cast<const bf16x8*>(
          ptsb + (size_t)(mbase + t * 16 + lr) * DIM + h * 32 + lg * 8);

  // DMA staging: LDS dest wave-uniform (HW adds lane*16); global source
  // per-lane, pre-swizzled (bits 7..9 of P are lane bits 3..5).
  const char* gbase = (const char*)spb + (size_t)s * SLN * DIM * 2;
  const int srcswz = ((lane >> 3) & 7) << 4;

#define STAGE(r, c)                                                          \
  {                                                                          \
    const char* g = gbase + (size_t)(r) * BUFBYTES;                          \
    _Pragma("unroll") for (int k = 0; k < 4; ++k) {                          \
      int P = wave * 4096 + k * 1024 + lane * 16;                            \
      char* ldst = ldsb + (c) * BUFBYTES + wave * 4096 + k * 1024;           \
      __builtin_amdgcn_global_load_lds(                                      \
          (const __attribute__((address_space(1))) void*)(g + (P ^ srcswz)), \
          (__attribute__((address_space(3))) void*)ldst, 16, 0, 0);          \
    }                                                                        \
  }

#define LDE(q0, q1, st)                                                      \
  e0 = *reinterpret_cast<const bf16x8*>((q0) + (st) * 2048);                 \
  e1 = *reinterpret_cast<const bf16x8*>((q1) + (st) * 2048);

#define LDO(q0, q1, st)                                                      \
  o0 = *reinterpret_cast<const bf16x8*>((q0) + (st) * 2048);                 \
  o1 = *reinterpret_cast<const bf16x8*>((q1) + (st) * 2048);

#define MS(C, B0, B1)                                                        \
  {                                                                          \
    _Pragma("unroll") for (int t = 0; t < 4; ++t) {                          \
      C[t] = __builtin_amdgcn_mfma_f32_16x16x32_bf16(a[t][0], B0, kz,        \
                                                     0, 0, 0);               \
      C[t] = __builtin_amdgcn_mfma_f32_16x16x32_bf16(a[t][1], B1, C[t],      \
                                                     0, 0, 0);               \
    }                                                                        \
  }

#define FINV(C, EN)                                                          \
  {                                                                          \
    float en = (EN);                                                         \
    _Pragma("unroll") for (int t = 0; t < 4; ++t) {                          \
      _Pragma("unroll") for (int rr = 0; rr < 4; ++rr) {                     \
        float e;                                                             \
        asm("v_exp_f32 %0, %1" : "=v"(e) : "v"(C[t][rr]));                   \
        sum[t][rr] = fmaf(en, e, sum[t][rr]);                                \
      }                                                                      \
    }                                                                        \
  }

#define FING(C, G) FINV(C, enp[(G) * 16])

  const f32x4 kz = {0.0f, 0.0f, 0.0f, 0.0f};  // shared C-init quad
  float sum[4][4] = {{0.0f, 0.0f, 0.0f, 0.0f}, {0.0f, 0.0f, 0.0f, 0.0f},
                     {0.0f, 0.0f, 0.0f, 0.0f}, {0.0f, 0.0f, 0.0f, 0.0f}};
  f32x4 cA[4], cB[4];
  bf16x8 e0, e1, o0, o1;

  // Swizzled read pointers (b1 = +64 swizzled separately; the st*2048 step
  // stride and the 16K buffer-select bit commute with the XOR on bits 4..6).
  const int swz = (lr & 7) << 4;
  const char* pb0 = ldsb + ((lr * 128 + lg * 16) ^ swz);
  const char* pb1 = ldsb + ((lr * 128 + 64 + lg * 16) ^ swz);
  const float* enp = lden + lr;

  STAGE(0, 0)
  asm volatile("s_waitcnt vmcnt(0)" ::: "memory");
  __syncthreads();

  LDE(pb0, pb1, 0)  // prologue: step-0 fragments of round 0

#pragma unroll
  for (int r = 0; r < ROUNDS; ++r) {
    const char* q0 = pb0 + (r & 1) * BUFBYTES;
    const char* q1 = pb1 + (r & 1) * BUFBYTES;

    LDO(q0, q1, 1)
    MS(cA, e0, e1)                    // st0
    LDE(q0, q1, 2)
    MS(cB, o0, o1) FING(cA, r * 8 + 0)  // st1
    LDO(q0, q1, 3)
    MS(cA, e0, e1) FING(cB, r * 8 + 1)  // st2
    LDE(q0, q1, 4)
    MS(cB, o0, o1) FING(cA, r * 8 + 2)  // st3
    LDO(q0, q1, 5)
    MS(cA, e0, e1) FING(cB, r * 8 + 3)  // st4
    LDE(q0, q1, 6)
    MS(cB, o0, o1) FING(cA, r * 8 + 4)  // st5

    // Everything the post-STAGE code needs from LDS, loaded BEFORE the DMA.
    float en5 = enp[(r * 8 + 5) * 16];
    float en6 = enp[(r * 8 + 6) * 16];
    float en7 = enp[(r * 8 + 7) * 16];
    LDO(q0, q1, 7)

    if (r + 1 < ROUNDS) {
      STAGE(r + 1, (r + 1) & 1)       // DMA next round; no ds_read follows
    }

    MS(cA, e0, e1) FINV(cB, en5)      // st6
    MS(cB, o0, o1) FINV(cA, en6)      // st7

    if (r + 1 < ROUNDS) {
      asm volatile("s_waitcnt vmcnt(0)" ::: "memory");
      __syncthreads();
      const char* n0 = pb0 + ((r + 1) & 1) * BUFBYTES;
      const char* n1 = pb1 + ((r + 1) & 1) * BUFBYTES;
      LDE(n0, n1, 0)                  // next round st0, covered by FINV below
    }
    FINV(cB, en7)
  }
#undef STAGE
#undef LDE
#undef LDO
#undef MS
#undef FINV
#undef FING

  // Reduce the 16 n-columns held across lanes of each k-group.
#pragma unroll
  for (int t = 0; t < 4; ++t)
#pragma unroll
    for (int r = 0; r < 4; ++r) {
      float v = sum[t][r];
      v += __shfl_xor(v, 1);
      v += __shfl_xor(v, 2);
      v += __shfl_xor(v, 4);
      v += __shfl_xor(v, 8);
      sum[t][r] = v;
    }
  if (lr == 0) {
#pragma unroll
    for (int t = 0; t < 4; ++t)
#pragma unroll
      for (int r = 0; r < 4; ++r) {
        int row = mbase + t * 16 + lg * 4 + r;
        partials[(size_t)s * M_PTS + row] = sum[t][r];
      }
  }
}

__global__ __launch_bounds__(256) void kde_reduce(
    const float* __restrict__ partials, const float* __restrict__ Em,
    float* __restrict__ out) {
  int m = blockIdx.x * 256 + threadIdx.x;
  float t = 0.0f;
#pragma unroll
  for (int s2 = 0; s2 < NSL; ++s2)
    t += partials[(size_t)s2 * M_PTS + m];
  out[m] = Em[m] * t;
}

extern "C" void kernel_launch(void* const* d_in, const int* in_sizes, int n_in,
                              void* d_out, int out_size, void* d_ws, size_t ws_size,
                              hipStream_t stream) {
  const float* pts = (const float*)d_in[0];   // [M, 64]
  const float* spt = (const float*)d_in[1];   // [N, 64]
  const float* w   = (const float*)d_in[2];   // [N]
  const float* bw  = (const float*)d_in[3];   // scalar
  float* out = (float*)d_out;                 // [M] fp32

  // ws: ptsb 2MB | spb 2MB | Em 64KB | En 64KB | partials 1MB
  char* ws = (char*)d_ws;
  unsigned short* ptsb = (unsigned short*)ws;
  unsigned short* spb  = (unsigned short*)(ws + (size_t)M_PTS * DIM * 2);
  float* Em = (float*)(ws + (size_t)(M_PTS + N_SPT) * DIM * 2);
  float* En = Em + M_PTS;
  float* partials = En + N_SPT;

  kde_prep<<<dim3((M_PTS + N_SPT) / 16), 256, 0, stream>>>(
      pts, spt, w, bw, ptsb, spb, Em, En);
  kde_main<<<dim3(M_PTS / 256, NSL), 256, 0, stream>>>(
      ptsb, spb, En, partials);
  kde_reduce<<<dim3(M_PTS / 256), 256, 0, stream>>>(partials, Em, out);
}

// Round 6
// 60.089 us; speedup vs baseline: 1.4821x; 1.1863x over previous
//
#include <hip/hip_runtime.h>
#include <hip/hip_bf16.h>

#define M_PTS 16384
#define N_SPT 16384
#define DIM   64
#define NSL   16                      // n-slices (blockIdx.y)
#define SLN   (N_SPT / NSL)           // 1024 n-rows per block
#define BUFROWS 128                   // n-rows per stage round
#define BUFBYTES (BUFROWS * DIM * 2)  // 16 KB per buffer
#define ROUNDS (SLN / BUFROWS)        // 8
#define STEPS  (BUFROWS / 16)         // 8 MFMA steps per round

typedef __attribute__((ext_vector_type(8))) short bf16x8;
typedef __attribute__((ext_vector_type(4))) float f32x4;

#define LOG2E 1.4426950408889634f

__device__ __forceinline__ unsigned short f32_bf16_rne(float f) {
  unsigned int x = __float_as_uint(f);
  x = x + 0x7fffu + ((x >> 16) & 1u);
  return (unsigned short)(x >> 16);
}
__device__ __forceinline__ float bf16_f32(unsigned short u) {
  return __uint_as_float(((unsigned int)u) << 16);
}

// Prep (unchanged, known-good):
//  points : store p~ = bf16(scale * p); Em = exp2(-|p~|^2/(2*scale))
//  spatial: store s~ = bf16(s); En = w * exp2(-|s~|^2 * scale/2)
// Em*En*exp2(p~ . s~) == exact Gaussian of the rounded points.
__global__ __launch_bounds__(256) void kde_prep(
    const float* __restrict__ pts, const float* __restrict__ spt,
    const float* __restrict__ w, const float* __restrict__ bw,
    unsigned short* __restrict__ ptsb, unsigned short* __restrict__ spb,
    float* __restrict__ Em, float* __restrict__ En) {
  const float b = bw[0];
  const float scale = LOG2E / (b * b);
  const float c1 = 0.5f * scale;
  const float invc = (b * b) / (2.0f * LOG2E);
  const int tid = threadIdx.x;
  const bool isP = blockIdx.x < (M_PTS / 16);
  const int r0 = isP ? (blockIdx.x * 16) : ((blockIdx.x - M_PTS / 16) * 16);
  const float* __restrict__ src = isP ? pts : spt;
  unsigned short* __restrict__ dst = isP ? ptsb : spb;

  size_t off = (size_t)r0 * DIM + (size_t)tid * 4;
  float4 v = *reinterpret_cast<const float4*>(src + off);
  if (isP) { v.x *= scale; v.y *= scale; v.z *= scale; v.w *= scale; }
  ushort4 u;
  u.x = f32_bf16_rne(v.x); u.y = f32_bf16_rne(v.y);
  u.z = f32_bf16_rne(v.z); u.w = f32_bf16_rne(v.w);
  float ax = bf16_f32(u.x), ay = bf16_f32(u.y);
  float az = bf16_f32(u.z), aw = bf16_f32(u.w);
  float sq = ax * ax + ay * ay + az * az + aw * aw;
  *reinterpret_cast<ushort4*>(dst + off) = u;

  sq += __shfl_xor(sq, 1);
  sq += __shfl_xor(sq, 2);
  sq += __shfl_xor(sq, 4);
  sq += __shfl_xor(sq, 8);
  if ((tid & 15) == 0) {
    int row = r0 + (tid >> 4);
    if (isP) Em[row] = exp2f(-sq * invc);
    else     En[row] = w[row] * exp2f(-sq * c1);
  }
}

// Main v7 = v0 (60.5us baseline) + three surgical deltas, nothing else:
//  1) kz C-init: MFMA step 0 accumulates into a shared zero quad instead of
//     re-zeroing 16 acc regs per step (-16 v_mov/step, ~12% of VALU load).
//  2) E/O register double-buffer: ds_reads for step st+1 issue before step
//     st's MFMA+FIN -> each ds_read pair has ~250 cyc of lgkm shadow
//     (v0 read fragments immediately before their MFMAs, exposing ~120 cyc
//     per step). Costs 16 VGPRs.
//  3) Post-barrier LDE of next round's step-0 fragments, covered by the
//     trailing FIN.
// Round loop stays ROLLED (v6's #pragma unroll -> 192 VGPR, occupancy
// halved, 97us). No __launch_bounds__ min-waves cap (v4-vs-v5 A/B: the
// (256,4) cap under pressure = spill corruption). v0 sync structure
// untouched: STAGE at round top, vmcnt(0)+barrier at round bottom.
__global__ __launch_bounds__(256) void kde_main(
    const unsigned short* __restrict__ ptsb,
    const unsigned short* __restrict__ spb,
    const float* __restrict__ En,
    float* __restrict__ partials) {
  __shared__ __align__(16) char ldsb[2 * BUFBYTES];  // 32 KB double buffer
  __shared__ float lden[SLN];                        // 4 KB En slice

  const int tid = threadIdx.x;
  const int lane = tid & 63;
  const int wave = tid >> 6;
  const int lr = lane & 15;   // tile row (A) / tile col (B)
  const int lg = lane >> 4;   // k-group
  const int mbase = blockIdx.x * 256 + wave * 64;
  const int s = blockIdx.y;

#pragma unroll
  for (int k = 0; k < SLN / 256; ++k)
    lden[tid + k * 256] = En[s * SLN + tid + k * 256];

  // A fragments (read once; 32 VGPRs).
  bf16x8 a[4][2];
#pragma unroll
  for (int t = 0; t < 4; ++t)
#pragma unroll
    for (int h = 0; h < 2; ++h)
      a[t][h] = *reinterpret_cast<const bf16x8*>(
          ptsb + (size_t)(mbase + t * 16 + lr) * DIM + h * 32 + lg * 8);

  // DMA staging: LDS dest wave-uniform (HW adds lane*16); global source
  // per-lane, pre-swizzled (bits 7..9 of P are lane bits 3..5).
  const char* gbase = (const char*)spb + (size_t)s * SLN * DIM * 2;
  const int srcswz = ((lane >> 3) & 7) << 4;

#define STAGE(r, c)                                                          \
  {                                                                          \
    const char* g = gbase + (size_t)(r) * BUFBYTES;                          \
    _Pragma("unroll") for (int k = 0; k < 4; ++k) {                          \
      int P = wave * 4096 + k * 1024 + lane * 16;                            \
      char* ldst = ldsb + (c) * BUFBYTES + wave * 4096 + k * 1024;           \
      __builtin_amdgcn_global_load_lds(                                      \
          (const __attribute__((address_space(1))) void*)(g + (P ^ srcswz)), \
          (__attribute__((address_space(3))) void*)ldst, 16, 0, 0);          \
    }                                                                        \
  }

#define LDE(q0, q1, st)                                                      \
  e0 = *reinterpret_cast<const bf16x8*>((q0) + (st) * 2048);                 \
  e1 = *reinterpret_cast<const bf16x8*>((q1) + (st) * 2048);

#define LDO(q0, q1, st)                                                      \
  o0 = *reinterpret_cast<const bf16x8*>((q0) + (st) * 2048);                 \
  o1 = *reinterpret_cast<const bf16x8*>((q1) + (st) * 2048);

#define MS(C, B0, B1)                                                        \
  {                                                                          \
    _Pragma("unroll") for (int t = 0; t < 4; ++t) {                          \
      C[t] = __builtin_amdgcn_mfma_f32_16x16x32_bf16(a[t][0], B0, kz,        \
                                                     0, 0, 0);               \
      C[t] = __builtin_amdgcn_mfma_f32_16x16x32_bf16(a[t][1], B1, C[t],      \
                                                     0, 0, 0);               \
    }                                                                        \
  }

#define FIN(C, EN)                                                           \
  {                                                                          \
    float en = (EN);                                                         \
    _Pragma("unroll") for (int t = 0; t < 4; ++t) {                          \
      _Pragma("unroll") for (int rr = 0; rr < 4; ++rr) {                     \
        float e;                                                             \
        asm("v_exp_f32 %0, %1" : "=v"(e) : "v"(C[t][rr]));                   \
        sum[t][rr] = fmaf(en, e, sum[t][rr]);                                \
      }                                                                      \
    }                                                                        \
  }

  const f32x4 kz = {0.0f, 0.0f, 0.0f, 0.0f};  // shared C-init quad
  float sum[4][4] = {{0.0f, 0.0f, 0.0f, 0.0f}, {0.0f, 0.0f, 0.0f, 0.0f},
                     {0.0f, 0.0f, 0.0f, 0.0f}, {0.0f, 0.0f, 0.0f, 0.0f}};
  f32x4 cA[4], cB[4];
  bf16x8 e0, e1, o0, o1;

  // Swizzled read pointers (b1 = +64 swizzled separately; the st*2048 step
  // stride and the 16K buffer-select bit commute with the XOR on bits 4..6).
  const int swz = (lr & 7) << 4;
  const char* pb0 = ldsb + ((lr * 128 + lg * 16) ^ swz);
  const char* pb1 = ldsb + ((lr * 128 + 64 + lg * 16) ^ swz);

  STAGE(0, 0)
  asm volatile("s_waitcnt vmcnt(0)" ::: "memory");
  __syncthreads();

  LDE(pb0, pb1, 0)  // prologue: step-0 fragments of round 0

  for (int r = 0; r < ROUNDS; ++r) {
    if (r + 1 < ROUNDS) {
      STAGE(r + 1, (r + 1) & 1)   // DMA next round into idle buffer
    }
    const char* q0 = pb0 + (r & 1) * BUFBYTES;
    const char* q1 = pb1 + (r & 1) * BUFBYTES;
    const float* er = lden + r * BUFROWS + lr;

    LDO(q0, q1, 1)
    MS(cA, e0, e1)                      // st0
    LDE(q0, q1, 2)
    MS(cB, o0, o1) FIN(cA, er[0 * 16])  // st1
    LDO(q0, q1, 3)
    MS(cA, e0, e1) FIN(cB, er[1 * 16])  // st2
    LDE(q0, q1, 4)
    MS(cB, o0, o1) FIN(cA, er[2 * 16])  // st3
    LDO(q0, q1, 5)
    MS(cA, e0, e1) FIN(cB, er[3 * 16])  // st4
    LDE(q0, q1, 6)
    MS(cB, o0, o1) FIN(cA, er[4 * 16])  // st5
    LDO(q0, q1, 7)
    MS(cA, e0, e1) FIN(cB, er[5 * 16])  // st6
    MS(cB, o0, o1) FIN(cA, er[6 * 16])  // st7

    // Staged data for round r+1 must have landed; also fences buffer reuse.
    asm volatile("s_waitcnt vmcnt(0)" ::: "memory");
    __syncthreads();

    if (r + 1 < ROUNDS) {
      const char* n0 = pb0 + ((r + 1) & 1) * BUFBYTES;
      const char* n1 = pb1 + ((r + 1) & 1) * BUFBYTES;
      LDE(n0, n1, 0)                  // next round st0, covered by FIN below
    }
    FIN(cB, er[7 * 16])
  }
#undef STAGE
#undef LDE
#undef LDO
#undef MS
#undef FIN

  // Reduce the 16 n-columns held across lanes of each k-group.
#pragma unroll
  for (int t = 0; t < 4; ++t)
#pragma unroll
    for (int r = 0; r < 4; ++r) {
      float v = sum[t][r];
      v += __shfl_xor(v, 1);
      v += __shfl_xor(v, 2);
      v += __shfl_xor(v, 4);
      v += __shfl_xor(v, 8);
      sum[t][r] = v;
    }
  if (lr == 0) {
#pragma unroll
    for (int t = 0; t < 4; ++t)
#pragma unroll
      for (int r = 0; r < 4; ++r) {
        int row = mbase + t * 16 + lg * 4 + r;
        partials[(size_t)s * M_PTS + row] = sum[t][r];
      }
  }
}

__global__ __launch_bounds__(256) void kde_reduce(
    const float* __restrict__ partials, const float* __restrict__ Em,
    float* __restrict__ out) {
  int m = blockIdx.x * 256 + threadIdx.x;
  float t = 0.0f;
#pragma unroll
  for (int s2 = 0; s2 < NSL; ++s2)
    t += partials[(size_t)s2 * M_PTS + m];
  out[m] = Em[m] * t;
}

extern "C" void kernel_launch(void* const* d_in, const int* in_sizes, int n_in,
                              void* d_out, int out_size, void* d_ws, size_t ws_size,
                              hipStream_t stream) {
  const float* pts = (const float*)d_in[0];   // [M, 64]
  const float* spt = (const float*)d_in[1];   // [N, 64]
  const float* w   = (const float*)d_in[2];   // [N]
  const float* bw  = (const float*)d_in[3];   // scalar
  float* out = (float*)d_out;                 // [M] fp32

  // ws: ptsb 2MB | spb 2MB | Em 64KB | En 64KB | partials 1MB
  char* ws = (char*)d_ws;
  unsigned short* ptsb = (unsigned short*)ws;
  unsigned short* spb  = (unsigned short*)(ws + (size_t)M_PTS * DIM * 2);
  float* Em = (float*)(ws + (size_t)(M_PTS + N_SPT) * DIM * 2);
  float* En = Em + M_PTS;
  float* partials = En + N_SPT;

  kde_prep<<<dim3((M_PTS + N_SPT) / 16), 256, 0, stream>>>(
      pts, spt, w, bw, ptsb, spb, Em, En);
  kde_main<<<dim3(M_PTS / 256, NSL), 256, 0, stream>>>(
      ptsb, spb, En, partials);
  kde_reduce<<<dim3(M_PTS / 256), 256, 0, stream>>>(partials, Em, out);
}